// Round 12
// baseline (669.414 us; speedup 1.0000x reference)
//
#include <hip/hip_runtime.h>
#include <hip/hip_bf16.h>

// RNN wavefunction log-prob: N=128, B=8192, H=128, D=2 (one-hot). f32 in/out.
// R12 = R7 structure with MB=8: grid 1024 x 256 thr, __launch_bounds__(256,4)
// -> 4 independent blocks (barrier streams) per CU. R7/R8/R10 all plateaued
// at ~200us with 2 streams/CU and no pipe >58% busy: the limit is the
// per-block dependency chain + barrier phase-lock. MFMA m-dim carries 8
// garbage columns (finite, never read back as output). Weights in VGPRs
// (96), biases + dense head in LDS, one barrier/iter, logit-diffs deferred.

#define NSTEP 128
#define BTOT  8192
#define HID   128
#define MB    8             // valid samples per block
#define TM    16            // MFMA m-tile (rows in LDS h-state)
#define NBLK  (BTOT / MB)   // 1024
#define NTHR  256

typedef __attribute__((ext_vector_type(8))) short bf16x8;
typedef __attribute__((ext_vector_type(4))) float f32x4;
typedef __attribute__((ext_vector_type(2))) float f32x2;
typedef __attribute__((ext_vector_type(2))) unsigned uint32x2;

__device__ __forceinline__ short f2bf(float v) {
    unsigned u = __builtin_bit_cast(unsigned, v);
    u += 0x7FFFu + ((u >> 16) & 1u);
    return (short)(u >> 16);
}
// two f32 -> packed bf16x2 via v_cvt_pk_bf16_f32
__device__ __forceinline__ unsigned cvt2bf(float a, float b) {
    __hip_bfloat162 h2 = __float22bfloat162_rn(make_float2(a, b));
    unsigned u; __builtin_memcpy(&u, &h2, sizeof(u));
    return u;
}
// tanh on a pair: 2 exp + ONE rcp (shared via rcp(d0*d1)) + pk ops
__device__ __forceinline__ f32x2 tanh2(f32x2 x) {
    f32x2 z = x * 2.885390081777927f;            // 2x*log2(e)
    float e0 = __builtin_exp2f(z.x);
    float e1 = __builtin_exp2f(z.y);
    f32x2 d = {e0 + 1.0f, e1 + 1.0f};
    float r = __builtin_amdgcn_rcpf(d.x * d.y);
    f32x2 inv = {r * d.y, r * d.x};              // 1/d.x, 1/d.y
    return inv * -2.0f + 1.0f;                   // v_pk_fma
}

__global__ __launch_bounds__(NTHR, 4) void rnn_wf_kernel(
    const float* __restrict__ samples,  // (128, 8192, 2)
    const float* __restrict__ Wih0,     // (128, 2)
    const float* __restrict__ bih0,     // (128,)
    const float* __restrict__ Whh0,     // (128, 128)
    const float* __restrict__ bhh0,     // (128,)
    const float* __restrict__ Wih1,     // (128, 128)
    const float* __restrict__ bih1,     // (128,)
    const float* __restrict__ Whh1,     // (128, 128)
    const float* __restrict__ bhh1,     // (128,)
    const float* __restrict__ Wd,       // (2, 128)
    const float* __restrict__ bd,       // (2,)
    float* __restrict__ out)            // (1, 8192)
{
    __shared__ short sH0[2][TM * HID];
    __shared__ short sH1[2][TM * HID];
    __shared__ unsigned sMask[NSTEP];
    __shared__ float sLd[NSTEP * 17];            // logit diffs [t*17 + s]
    __shared__ __attribute__((aligned(16))) float sBias[4 * HID];
    // segments: [0:128)=WA (b0+Wih0 col0), [128:256)=WB (col1),
    //           [256:384)=B1, [384:512)=B0 plain
    __shared__ __attribute__((aligned(16))) short sFwd[4 * 64 * 8];

    const int tid  = threadIdx.x;
    const int b0   = blockIdx.x * MB;
    const int w    = tid >> 6;
    const int lane = tid & 63;
    const int q    = lane >> 4;
    const int c    = lane & 15;
    const int nb   = w * 32;

    // ---- decode f32 one-hot samples -> per-step 8-bit masks ----
    if (tid < NSTEP) {
        unsigned msk = 0;
        #pragma unroll
        for (int m = 0; m < MB; ++m) {
            float e1 = samples[((size_t)tid * BTOT + b0 + m) * 2 + 1];
            if (e1 > 0.5f) msk |= (1u << m);
        }
        sMask[tid] = msk;   // bits >= MB stay 0 -> garbage lanes take pA path
    }
    // ---- biases into LDS ----
    if (tid < HID) {
        const float bb = bih0[tid] + bhh0[tid];
        sBias[tid]       = bb + Wih0[tid * 2 + 0];
        sBias[128 + tid] = bb + Wih0[tid * 2 + 1];
        sBias[256 + tid] = bih1[tid] + bhh1[tid];
        sBias[384 + tid] = bb;
    }
    // ---- dense-head fragments into LDS (fragment layout, any wave reads) ----
    {
        const int kb = tid >> 6, l = tid & 63, cc = l & 15, qq = l >> 4;
        bf16x8 v;
        #pragma unroll
        for (int j = 0; j < 8; ++j)
            v[j] = (cc < 2) ? f2bf(Wd[cc * HID + kb * 32 + qq * 8 + j]) : (short)0;
        *reinterpret_cast<bf16x8*>(&sFwd[(kb * 64 + l) * 8]) = v;
    }

    // ---- weight A-fragments: lane holds W[nb+nt*16+c][kb*32+q*8 .. +8] ----
    bf16x8 fhh0[2][4], fih1[2][4], fhh1[2][4];
    #pragma unroll
    for (int nt = 0; nt < 2; ++nt) {
        const int nn = nb + nt * 16 + c;
        #pragma unroll
        for (int kb = 0; kb < 4; ++kb) {
            const int off = nn * HID + kb * 32 + q * 8;
            bf16x8 v0, v1, v2;
            #pragma unroll
            for (int j = 0; j < 8; ++j) {
                v0[j] = f2bf(Whh0[off + j]);
                v1[j] = f2bf(Wih1[off + j]);
                v2[j] = f2bf(Whh1[off + j]);
            }
            fhh0[nt][kb] = v0; fih1[nt][kb] = v1; fhh1[nt][kb] = v2;
        }
    }
    const float bd0 = bd[0], bd1 = bd[1];

    // ---- t-invariant LDS indices, full-c XOR swizzle (conflict-verified) ----
    int ra[4];
    #pragma unroll
    for (int kb = 0; kb < 4; ++kb)
        ra[kb] = c * HID + (((kb * 4 + q) ^ c) << 3);
    const int wa0 = c * HID + (((4 * w + (q >> 1)) ^ c) << 3) + ((q & 1) << 2);
    const int wa1 = c * HID + (((4 * w + 2 + (q >> 1)) ^ c) << 3) + ((q & 1) << 2);
    const int ib  = nb + q * 4;     // float index into bias arrays

    bool bmPrev = false;

    auto storeH = [&](short* buf, const f32x4& a0, const f32x4& a1) {
        f32x2 t00 = tanh2((f32x2){a0[0], a0[1]});
        f32x2 t01 = tanh2((f32x2){a0[2], a0[3]});
        f32x2 t10 = tanh2((f32x2){a1[0], a1[1]});
        f32x2 t11 = tanh2((f32x2){a1[2], a1[3]});
        uint32x2 v0 = {cvt2bf(t00.x, t00.y), cvt2bf(t01.x, t01.y)};
        uint32x2 v1 = {cvt2bf(t10.x, t10.y), cvt2bf(t11.x, t11.y)};
        *reinterpret_cast<uint32x2*>(&buf[wa0]) = v0;
        *reinterpret_cast<uint32x2*>(&buf[wa1]) = v1;
    };

    __syncthreads();                 // sMask, sBias, sFwd published

    // ---- i = 0: h0(0) = tanh(b0) ----
    {
        f32x4 c0 = *reinterpret_cast<const f32x4*>(&sBias[384 + ib]);
        f32x4 c1 = *reinterpret_cast<const f32x4*>(&sBias[384 + ib + 16]);
        storeH(sH0[1], c0, c1);      // writes all 16 rows (8 garbage, finite)
    }
    __syncthreads();

    // ---- i = 1: h0(1), h1(0) ----
    {
        const bool bmIn = (sMask[0] >> c) & 1u;
        const float* bp = bmIn ? (sBias + 128) : sBias;
        f32x4 a00 = *reinterpret_cast<const f32x4*>(&bp[ib]);
        f32x4 a01 = *reinterpret_cast<const f32x4*>(&bp[ib + 16]);
        f32x4 a10 = *reinterpret_cast<const f32x4*>(&sBias[256 + ib]);
        f32x4 a11 = *reinterpret_cast<const f32x4*>(&sBias[256 + ib + 16]);
        bf16x8 f0[4];
        #pragma unroll
        for (int kb = 0; kb < 4; ++kb)
            f0[kb] = *reinterpret_cast<const bf16x8*>(&sH0[1][ra[kb]]);
        #pragma unroll
        for (int kb = 0; kb < 4; ++kb) {
            a00 = __builtin_amdgcn_mfma_f32_16x16x32_bf16(fhh0[0][kb], f0[kb], a00, 0, 0, 0);
            a01 = __builtin_amdgcn_mfma_f32_16x16x32_bf16(fhh0[1][kb], f0[kb], a01, 0, 0, 0);
            a10 = __builtin_amdgcn_mfma_f32_16x16x32_bf16(fih1[0][kb], f0[kb], a10, 0, 0, 0);
            a11 = __builtin_amdgcn_mfma_f32_16x16x32_bf16(fih1[1][kb], f0[kb], a11, 0, 0, 0);
        }
        storeH(sH0[0], a00, a01);   // h0(1)
        storeH(sH1[0], a10, a11);   // h1(0)
        bmPrev = bmIn;
        __syncthreads();
    }

    // ---- main: i = 2..127, one barrier per iteration ----
    auto stepMain = [&](int i, const short* r0, const short* r1,
                        short* w0b, short* w1b) {
        const bool bmIn = (sMask[i - 1] >> c) & 1u;
        const float* bp = bmIn ? (sBias + 128) : sBias;
        f32x4 a00 = *reinterpret_cast<const f32x4*>(&bp[ib]);
        f32x4 a01 = *reinterpret_cast<const f32x4*>(&bp[ib + 16]);
        f32x4 a10 = *reinterpret_cast<const f32x4*>(&sBias[256 + ib]);
        f32x4 a11 = *reinterpret_cast<const f32x4*>(&sBias[256 + ib + 16]);
        bf16x8 f0[4], f1[4];
        #pragma unroll
        for (int kb = 0; kb < 4; ++kb) {
            f0[kb] = *reinterpret_cast<const bf16x8*>(&r0[ra[kb]]);
            f1[kb] = *reinterpret_cast<const bf16x8*>(&r1[ra[kb]]);
        }
        #pragma unroll
        for (int kb = 0; kb < 4; ++kb) {
            a00 = __builtin_amdgcn_mfma_f32_16x16x32_bf16(fhh0[0][kb], f0[kb], a00, 0, 0, 0);
            a01 = __builtin_amdgcn_mfma_f32_16x16x32_bf16(fhh0[1][kb], f0[kb], a01, 0, 0, 0);
            a10 = __builtin_amdgcn_mfma_f32_16x16x32_bf16(fhh1[0][kb], f1[kb], a10, 0, 0, 0);
            a11 = __builtin_amdgcn_mfma_f32_16x16x32_bf16(fhh1[1][kb], f1[kb], a11, 0, 0, 0);
        }
        #pragma unroll
        for (int kb = 0; kb < 4; ++kb) {
            a10 = __builtin_amdgcn_mfma_f32_16x16x32_bf16(fih1[0][kb], f0[kb], a10, 0, 0, 0);
            a11 = __builtin_amdgcn_mfma_f32_16x16x32_bf16(fih1[1][kb], f0[kb], a11, 0, 0, 0);
        }
        if (w == (i & 3)) {   // rotate logits duty across the 4 waves
            f32x4 aL = {bd0, bd1, 0.f, 0.f};
            #pragma unroll
            for (int kb = 0; kb < 4; ++kb) {
                bf16x8 fw = *reinterpret_cast<const bf16x8*>(&sFwd[(kb * 64 + lane) * 8]);
                aL = __builtin_amdgcn_mfma_f32_16x16x32_bf16(fw, f1[kb], aL, 0, 0, 0);
            }
            if (q == 0)
                sLd[(i - 2) * 17 + c] = bmPrev ? (aL[0] - aL[1]) : (aL[1] - aL[0]);
        }
        bmPrev = bmIn;
        storeH(w0b, a00, a01);              // h0(i)
        storeH(w1b, a10, a11);              // h1(i-1)
        __syncthreads();
    };

    for (int i = 2; i < NSTEP; i += 2) {
        stepMain(i,     sH0[0], sH1[0], sH0[1], sH1[1]);
        stepMain(i + 1, sH0[1], sH1[1], sH0[0], sH1[0]);
    }

    // ---- i = 128: h1(127), logits(126) ----
    {
        f32x4 a10 = *reinterpret_cast<const f32x4*>(&sBias[256 + ib]);
        f32x4 a11 = *reinterpret_cast<const f32x4*>(&sBias[256 + ib + 16]);
        bf16x8 f0[4], f1[4];
        #pragma unroll
        for (int kb = 0; kb < 4; ++kb) {
            f0[kb] = *reinterpret_cast<const bf16x8*>(&sH0[0][ra[kb]]);  // h0(127)
            f1[kb] = *reinterpret_cast<const bf16x8*>(&sH1[0][ra[kb]]);  // h1(126)
        }
        #pragma unroll
        for (int kb = 0; kb < 4; ++kb) {
            a10 = __builtin_amdgcn_mfma_f32_16x16x32_bf16(fhh1[0][kb], f1[kb], a10, 0, 0, 0);
            a11 = __builtin_amdgcn_mfma_f32_16x16x32_bf16(fhh1[1][kb], f1[kb], a11, 0, 0, 0);
        }
        #pragma unroll
        for (int kb = 0; kb < 4; ++kb) {
            a10 = __builtin_amdgcn_mfma_f32_16x16x32_bf16(fih1[0][kb], f0[kb], a10, 0, 0, 0);
            a11 = __builtin_amdgcn_mfma_f32_16x16x32_bf16(fih1[1][kb], f0[kb], a11, 0, 0, 0);
        }
        if (w == 0) {
            f32x4 aL = {bd0, bd1, 0.f, 0.f};
            #pragma unroll
            for (int kb = 0; kb < 4; ++kb) {
                bf16x8 fw = *reinterpret_cast<const bf16x8*>(&sFwd[(kb * 64 + lane) * 8]);
                aL = __builtin_amdgcn_mfma_f32_16x16x32_bf16(fw, f1[kb], aL, 0, 0, 0);
            }
            if (q == 0)
                sLd[126 * 17 + c] = bmPrev ? (aL[0] - aL[1]) : (aL[1] - aL[0]);
        }
        storeH(sH1[1], a10, a11);           // h1(127)
        __syncthreads();
    }
    // ---- i = 129: logits(127), wave 1 ----
    if (w == 1) {
        f32x4 aL = {bd0, bd1, 0.f, 0.f};
        #pragma unroll
        for (int kb = 0; kb < 4; ++kb) {
            bf16x8 f1 = *reinterpret_cast<const bf16x8*>(&sH1[1][ra[kb]]);
            bf16x8 fw = *reinterpret_cast<const bf16x8*>(&sFwd[(kb * 64 + lane) * 8]);
            aL = __builtin_amdgcn_mfma_f32_16x16x32_bf16(fw, f1, aL, 0, 0, 0);
        }
        if (q == 0) {
            const bool bit = (sMask[NSTEP - 1] >> c) & 1u;
            sLd[127 * 17 + c] = bit ? (aL[0] - aL[1]) : (aL[1] - aL[0]);
        }
    }
    __syncthreads();

    // ---- final pass: lp(s) = sum_t -log(1 + exp(diff_t)), s < MB ----
    if (tid < 16 * MB) {
        const int s = tid >> 4;       // sample 0..7
        const int k = tid & 15;       // step sub-index
        float acc = 0.0f;
        #pragma unroll
        for (int j = 0; j < 8; ++j) {
            const float x = sLd[(j * 16 + k) * 17 + s];
            const float ed = __builtin_exp2f(x * 1.4426950408889634f);
            acc -= 0.6931471805599453f * __builtin_log2f(1.0f + ed);
        }
        #pragma unroll
        for (int off = 1; off < 16; off <<= 1)
            acc += __shfl_xor(acc, off, 64);
        if (k == 0)
            out[b0 + s] = acc;
    }
}

extern "C" void kernel_launch(void* const* d_in, const int* in_sizes, int n_in,
                              void* d_out, int out_size, void* d_ws, size_t ws_size,
                              hipStream_t stream) {
    rnn_wf_kernel<<<NBLK, NTHR, 0, stream>>>(
        (const float*)d_in[0],  // samples
        (const float*)d_in[1],  // W_ih0
        (const float*)d_in[2],  // b_ih0
        (const float*)d_in[3],  // W_hh0
        (const float*)d_in[4],  // b_hh0
        (const float*)d_in[5],  // W_ih1
        (const float*)d_in[6],  // b_ih1
        (const float*)d_in[7],  // W_hh1
        (const float*)d_in[8],  // b_hh1
        (const float*)d_in[9],  // W_dense
        (const float*)d_in[10], // b_dense
        (float*)d_out);
}

// Round 13
// 393.607 us; speedup vs baseline: 1.7007x; 1.7007x over previous
//
#include <hip/hip_runtime.h>
#include <hip/hip_bf16.h>

// RNN wavefunction log-prob: N=128, B=8192, H=128, D=2 (one-hot). f32 in/out.
// R13 = R12 (MB=8, grid 1024, 4 blocks/CU) with __launch_bounds__(256,2):
// R12's (256,4) made the allocator over-comply down to 64 VGPRs and spill
// the weight fragments (FETCH 1.5 GB, HBM-bound). (256,2) yields VGPR~124
// (R7-proven) which still permits 4 waves/EU residency -> 4 independent
// barrier streams per CU with zero spill. Everything else identical to R12.

#define NSTEP 128
#define BTOT  8192
#define HID   128
#define MB    8             // valid samples per block
#define TM    16            // MFMA m-tile (rows in LDS h-state)
#define NBLK  (BTOT / MB)   // 1024
#define NTHR  256

typedef __attribute__((ext_vector_type(8))) short bf16x8;
typedef __attribute__((ext_vector_type(4))) float f32x4;
typedef __attribute__((ext_vector_type(2))) float f32x2;
typedef __attribute__((ext_vector_type(2))) unsigned uint32x2;

__device__ __forceinline__ short f2bf(float v) {
    unsigned u = __builtin_bit_cast(unsigned, v);
    u += 0x7FFFu + ((u >> 16) & 1u);
    return (short)(u >> 16);
}
// two f32 -> packed bf16x2 via v_cvt_pk_bf16_f32
__device__ __forceinline__ unsigned cvt2bf(float a, float b) {
    __hip_bfloat162 h2 = __float22bfloat162_rn(make_float2(a, b));
    unsigned u; __builtin_memcpy(&u, &h2, sizeof(u));
    return u;
}
// tanh on a pair: 2 exp + ONE rcp (shared via rcp(d0*d1)) + pk ops
__device__ __forceinline__ f32x2 tanh2(f32x2 x) {
    f32x2 z = x * 2.885390081777927f;            // 2x*log2(e)
    float e0 = __builtin_exp2f(z.x);
    float e1 = __builtin_exp2f(z.y);
    f32x2 d = {e0 + 1.0f, e1 + 1.0f};
    float r = __builtin_amdgcn_rcpf(d.x * d.y);
    f32x2 inv = {r * d.y, r * d.x};              // 1/d.x, 1/d.y
    return inv * -2.0f + 1.0f;                   // v_pk_fma
}

__global__ __launch_bounds__(NTHR, 2) void rnn_wf_kernel(
    const float* __restrict__ samples,  // (128, 8192, 2)
    const float* __restrict__ Wih0,     // (128, 2)
    const float* __restrict__ bih0,     // (128,)
    const float* __restrict__ Whh0,     // (128, 128)
    const float* __restrict__ bhh0,     // (128,)
    const float* __restrict__ Wih1,     // (128, 128)
    const float* __restrict__ bih1,     // (128,)
    const float* __restrict__ Whh1,     // (128, 128)
    const float* __restrict__ bhh1,     // (128,)
    const float* __restrict__ Wd,       // (2, 128)
    const float* __restrict__ bd,       // (2,)
    float* __restrict__ out)            // (1, 8192)
{
    __shared__ short sH0[2][TM * HID];
    __shared__ short sH1[2][TM * HID];
    __shared__ unsigned sMask[NSTEP];
    __shared__ float sLd[NSTEP * 17];            // logit diffs [t*17 + s]
    __shared__ __attribute__((aligned(16))) float sBias[4 * HID];
    // segments: [0:128)=WA (b0+Wih0 col0), [128:256)=WB (col1),
    //           [256:384)=B1, [384:512)=B0 plain
    __shared__ __attribute__((aligned(16))) short sFwd[4 * 64 * 8];

    const int tid  = threadIdx.x;
    const int b0   = blockIdx.x * MB;
    const int w    = tid >> 6;
    const int lane = tid & 63;
    const int q    = lane >> 4;
    const int c    = lane & 15;
    const int nb   = w * 32;

    // ---- decode f32 one-hot samples -> per-step 8-bit masks ----
    if (tid < NSTEP) {
        unsigned msk = 0;
        #pragma unroll
        for (int m = 0; m < MB; ++m) {
            float e1 = samples[((size_t)tid * BTOT + b0 + m) * 2 + 1];
            if (e1 > 0.5f) msk |= (1u << m);
        }
        sMask[tid] = msk;   // bits >= MB stay 0 -> garbage lanes take pA path
    }
    // ---- biases into LDS ----
    if (tid < HID) {
        const float bb = bih0[tid] + bhh0[tid];
        sBias[tid]       = bb + Wih0[tid * 2 + 0];
        sBias[128 + tid] = bb + Wih0[tid * 2 + 1];
        sBias[256 + tid] = bih1[tid] + bhh1[tid];
        sBias[384 + tid] = bb;
    }
    // ---- dense-head fragments into LDS (fragment layout, any wave reads) ----
    {
        const int kb = tid >> 6, l = tid & 63, cc = l & 15, qq = l >> 4;
        bf16x8 v;
        #pragma unroll
        for (int j = 0; j < 8; ++j)
            v[j] = (cc < 2) ? f2bf(Wd[cc * HID + kb * 32 + qq * 8 + j]) : (short)0;
        *reinterpret_cast<bf16x8*>(&sFwd[(kb * 64 + l) * 8]) = v;
    }

    // ---- weight A-fragments: lane holds W[nb+nt*16+c][kb*32+q*8 .. +8] ----
    bf16x8 fhh0[2][4], fih1[2][4], fhh1[2][4];
    #pragma unroll
    for (int nt = 0; nt < 2; ++nt) {
        const int nn = nb + nt * 16 + c;
        #pragma unroll
        for (int kb = 0; kb < 4; ++kb) {
            const int off = nn * HID + kb * 32 + q * 8;
            bf16x8 v0, v1, v2;
            #pragma unroll
            for (int j = 0; j < 8; ++j) {
                v0[j] = f2bf(Whh0[off + j]);
                v1[j] = f2bf(Wih1[off + j]);
                v2[j] = f2bf(Whh1[off + j]);
            }
            fhh0[nt][kb] = v0; fih1[nt][kb] = v1; fhh1[nt][kb] = v2;
        }
    }
    const float bd0 = bd[0], bd1 = bd[1];

    // ---- t-invariant LDS indices, full-c XOR swizzle (conflict-verified) ----
    int ra[4];
    #pragma unroll
    for (int kb = 0; kb < 4; ++kb)
        ra[kb] = c * HID + (((kb * 4 + q) ^ c) << 3);
    const int wa0 = c * HID + (((4 * w + (q >> 1)) ^ c) << 3) + ((q & 1) << 2);
    const int wa1 = c * HID + (((4 * w + 2 + (q >> 1)) ^ c) << 3) + ((q & 1) << 2);
    const int ib  = nb + q * 4;     // float index into bias arrays

    bool bmPrev = false;

    auto storeH = [&](short* buf, const f32x4& a0, const f32x4& a1) {
        f32x2 t00 = tanh2((f32x2){a0[0], a0[1]});
        f32x2 t01 = tanh2((f32x2){a0[2], a0[3]});
        f32x2 t10 = tanh2((f32x2){a1[0], a1[1]});
        f32x2 t11 = tanh2((f32x2){a1[2], a1[3]});
        uint32x2 v0 = {cvt2bf(t00.x, t00.y), cvt2bf(t01.x, t01.y)};
        uint32x2 v1 = {cvt2bf(t10.x, t10.y), cvt2bf(t11.x, t11.y)};
        *reinterpret_cast<uint32x2*>(&buf[wa0]) = v0;
        *reinterpret_cast<uint32x2*>(&buf[wa1]) = v1;
    };

    __syncthreads();                 // sMask, sBias, sFwd published

    // ---- i = 0: h0(0) = tanh(b0) ----
    {
        f32x4 c0 = *reinterpret_cast<const f32x4*>(&sBias[384 + ib]);
        f32x4 c1 = *reinterpret_cast<const f32x4*>(&sBias[384 + ib + 16]);
        storeH(sH0[1], c0, c1);      // writes all 16 rows (8 garbage, finite)
    }
    __syncthreads();

    // ---- i = 1: h0(1), h1(0) ----
    {
        const bool bmIn = (sMask[0] >> c) & 1u;
        const float* bp = bmIn ? (sBias + 128) : sBias;
        f32x4 a00 = *reinterpret_cast<const f32x4*>(&bp[ib]);
        f32x4 a01 = *reinterpret_cast<const f32x4*>(&bp[ib + 16]);
        f32x4 a10 = *reinterpret_cast<const f32x4*>(&sBias[256 + ib]);
        f32x4 a11 = *reinterpret_cast<const f32x4*>(&sBias[256 + ib + 16]);
        bf16x8 f0[4];
        #pragma unroll
        for (int kb = 0; kb < 4; ++kb)
            f0[kb] = *reinterpret_cast<const bf16x8*>(&sH0[1][ra[kb]]);
        #pragma unroll
        for (int kb = 0; kb < 4; ++kb) {
            a00 = __builtin_amdgcn_mfma_f32_16x16x32_bf16(fhh0[0][kb], f0[kb], a00, 0, 0, 0);
            a01 = __builtin_amdgcn_mfma_f32_16x16x32_bf16(fhh0[1][kb], f0[kb], a01, 0, 0, 0);
            a10 = __builtin_amdgcn_mfma_f32_16x16x32_bf16(fih1[0][kb], f0[kb], a10, 0, 0, 0);
            a11 = __builtin_amdgcn_mfma_f32_16x16x32_bf16(fih1[1][kb], f0[kb], a11, 0, 0, 0);
        }
        storeH(sH0[0], a00, a01);   // h0(1)
        storeH(sH1[0], a10, a11);   // h1(0)
        bmPrev = bmIn;
        __syncthreads();
    }

    // ---- main: i = 2..127, one barrier per iteration ----
    auto stepMain = [&](int i, const short* r0, const short* r1,
                        short* w0b, short* w1b) {
        const bool bmIn = (sMask[i - 1] >> c) & 1u;
        const float* bp = bmIn ? (sBias + 128) : sBias;
        f32x4 a00 = *reinterpret_cast<const f32x4*>(&bp[ib]);
        f32x4 a01 = *reinterpret_cast<const f32x4*>(&bp[ib + 16]);
        f32x4 a10 = *reinterpret_cast<const f32x4*>(&sBias[256 + ib]);
        f32x4 a11 = *reinterpret_cast<const f32x4*>(&sBias[256 + ib + 16]);
        bf16x8 f0[4], f1[4];
        #pragma unroll
        for (int kb = 0; kb < 4; ++kb) {
            f0[kb] = *reinterpret_cast<const bf16x8*>(&r0[ra[kb]]);
            f1[kb] = *reinterpret_cast<const bf16x8*>(&r1[ra[kb]]);
        }
        #pragma unroll
        for (int kb = 0; kb < 4; ++kb) {
            a00 = __builtin_amdgcn_mfma_f32_16x16x32_bf16(fhh0[0][kb], f0[kb], a00, 0, 0, 0);
            a01 = __builtin_amdgcn_mfma_f32_16x16x32_bf16(fhh0[1][kb], f0[kb], a01, 0, 0, 0);
            a10 = __builtin_amdgcn_mfma_f32_16x16x32_bf16(fhh1[0][kb], f1[kb], a10, 0, 0, 0);
            a11 = __builtin_amdgcn_mfma_f32_16x16x32_bf16(fhh1[1][kb], f1[kb], a11, 0, 0, 0);
        }
        #pragma unroll
        for (int kb = 0; kb < 4; ++kb) {
            a10 = __builtin_amdgcn_mfma_f32_16x16x32_bf16(fih1[0][kb], f0[kb], a10, 0, 0, 0);
            a11 = __builtin_amdgcn_mfma_f32_16x16x32_bf16(fih1[1][kb], f0[kb], a11, 0, 0, 0);
        }
        if (w == (i & 3)) {   // rotate logits duty across the 4 waves
            f32x4 aL = {bd0, bd1, 0.f, 0.f};
            #pragma unroll
            for (int kb = 0; kb < 4; ++kb) {
                bf16x8 fw = *reinterpret_cast<const bf16x8*>(&sFwd[(kb * 64 + lane) * 8]);
                aL = __builtin_amdgcn_mfma_f32_16x16x32_bf16(fw, f1[kb], aL, 0, 0, 0);
            }
            if (q == 0)
                sLd[(i - 2) * 17 + c] = bmPrev ? (aL[0] - aL[1]) : (aL[1] - aL[0]);
        }
        bmPrev = bmIn;
        storeH(w0b, a00, a01);              // h0(i)
        storeH(w1b, a10, a11);              // h1(i-1)
        __syncthreads();
    };

    for (int i = 2; i < NSTEP; i += 2) {
        stepMain(i,     sH0[0], sH1[0], sH0[1], sH1[1]);
        stepMain(i + 1, sH0[1], sH1[1], sH0[0], sH1[0]);
    }

    // ---- i = 128: h1(127), logits(126) ----
    {
        f32x4 a10 = *reinterpret_cast<const f32x4*>(&sBias[256 + ib]);
        f32x4 a11 = *reinterpret_cast<const f32x4*>(&sBias[256 + ib + 16]);
        bf16x8 f0[4], f1[4];
        #pragma unroll
        for (int kb = 0; kb < 4; ++kb) {
            f0[kb] = *reinterpret_cast<const bf16x8*>(&sH0[0][ra[kb]]);  // h0(127)
            f1[kb] = *reinterpret_cast<const bf16x8*>(&sH1[0][ra[kb]]);  // h1(126)
        }
        #pragma unroll
        for (int kb = 0; kb < 4; ++kb) {
            a10 = __builtin_amdgcn_mfma_f32_16x16x32_bf16(fhh1[0][kb], f1[kb], a10, 0, 0, 0);
            a11 = __builtin_amdgcn_mfma_f32_16x16x32_bf16(fhh1[1][kb], f1[kb], a11, 0, 0, 0);
        }
        #pragma unroll
        for (int kb = 0; kb < 4; ++kb) {
            a10 = __builtin_amdgcn_mfma_f32_16x16x32_bf16(fih1[0][kb], f0[kb], a10, 0, 0, 0);
            a11 = __builtin_amdgcn_mfma_f32_16x16x32_bf16(fih1[1][kb], f0[kb], a11, 0, 0, 0);
        }
        if (w == 0) {
            f32x4 aL = {bd0, bd1, 0.f, 0.f};
            #pragma unroll
            for (int kb = 0; kb < 4; ++kb) {
                bf16x8 fw = *reinterpret_cast<const bf16x8*>(&sFwd[(kb * 64 + lane) * 8]);
                aL = __builtin_amdgcn_mfma_f32_16x16x32_bf16(fw, f1[kb], aL, 0, 0, 0);
            }
            if (q == 0)
                sLd[126 * 17 + c] = bmPrev ? (aL[0] - aL[1]) : (aL[1] - aL[0]);
        }
        storeH(sH1[1], a10, a11);           // h1(127)
        __syncthreads();
    }
    // ---- i = 129: logits(127), wave 1 ----
    if (w == 1) {
        f32x4 aL = {bd0, bd1, 0.f, 0.f};
        #pragma unroll
        for (int kb = 0; kb < 4; ++kb) {
            bf16x8 f1 = *reinterpret_cast<const bf16x8*>(&sH1[1][ra[kb]]);
            bf16x8 fw = *reinterpret_cast<const bf16x8*>(&sFwd[(kb * 64 + lane) * 8]);
            aL = __builtin_amdgcn_mfma_f32_16x16x32_bf16(fw, f1, aL, 0, 0, 0);
        }
        if (q == 0) {
            const bool bit = (sMask[NSTEP - 1] >> c) & 1u;
            sLd[127 * 17 + c] = bit ? (aL[0] - aL[1]) : (aL[1] - aL[0]);
        }
    }
    __syncthreads();

    // ---- final pass: lp(s) = sum_t -log(1 + exp(diff_t)), s < MB ----
    if (tid < 16 * MB) {
        const int s = tid >> 4;       // sample 0..7
        const int k = tid & 15;       // step sub-index
        float acc = 0.0f;
        #pragma unroll
        for (int j = 0; j < 8; ++j) {
            const float x = sLd[(j * 16 + k) * 17 + s];
            const float ed = __builtin_exp2f(x * 1.4426950408889634f);
            acc -= 0.6931471805599453f * __builtin_log2f(1.0f + ed);
        }
        #pragma unroll
        for (int off = 1; off < 16; off <<= 1)
            acc += __shfl_xor(acc, off, 64);
        if (k == 0)
            out[b0 + s] = acc;
    }
}

extern "C" void kernel_launch(void* const* d_in, const int* in_sizes, int n_in,
                              void* d_out, int out_size, void* d_ws, size_t ws_size,
                              hipStream_t stream) {
    rnn_wf_kernel<<<NBLK, NTHR, 0, stream>>>(
        (const float*)d_in[0],  // samples
        (const float*)d_in[1],  // W_ih0
        (const float*)d_in[2],  // b_ih0
        (const float*)d_in[3],  // W_hh0
        (const float*)d_in[4],  // b_hh0
        (const float*)d_in[5],  // W_ih1
        (const float*)d_in[6],  // b_ih1
        (const float*)d_in[7],  // W_hh1
        (const float*)d_in[8],  // b_hh1
        (const float*)d_in[9],  // W_dense
        (const float*)d_in[10], // b_dense
        (float*)d_out);
}